// Round 3
// baseline (1512.938 us; speedup 1.0000x reference)
//
#include <hip/hip_runtime.h>
#include <math.h>

#define NN 100000
#define NE 3200000
#define NG 1024
#define FDIM 128
#define NFC1 64
#define NFC2 10

#define BSHIFT 9
#define NBUCK 196   // ceil(NN/512)
#define CAP 20480   // mean 16384, sigma ~127 -> 32-sigma headroom
#define EPB 16      // edges per thread in bin_kernel

// Feature slicing: agg is linear and per-feature independent after the
// y = x@W swap, so partition features into 16 slices of 8 floats (32B).
// One slice = 3.2 MB -> L2-resident per XCD. Slice s binds to XCD s%8 via
// round-robin dispatch (bid%8); two time-separated phases cover 16 slices.
#define NS 16
#define FS 8
#define SS 800000        // slice stride in floats = NN*FS (3.2 MB)
#define AGG_TILE 128     // dst rows per agg block
#define AGG_NT 782       // ceil(NN/128)

// ---------------- pass 1: bin edges into 196 coarse buckets ----------------
__global__ __launch_bounds__(256) void bin_kernel(const int* __restrict__ src,
                                                  const int* __restrict__ dst,
                                                  int* __restrict__ gcursor,
                                                  int* __restrict__ staging) {
  __shared__ int hist[NBUCK];
  __shared__ int base[NBUCK];
  int t = threadIdx.x;
  for (int i = t; i < NBUCK; i += 256) hist[i] = 0;
  __syncthreads();
  size_t e0 = (size_t)blockIdx.x * (256 * EPB);
  int bk[EPB], rank[EPB], val[EPB];
#pragma unroll
  for (int j = 0; j < EPB; ++j) {
    size_t e = e0 + (size_t)j * 256 + t;
    if (e < NE) {
      int d = dst[e];
      int s = src[e];
      bk[j] = d >> BSHIFT;
      val[j] = ((d & 511) << 17) | s;
      rank[j] = atomicAdd(&hist[bk[j]], 1);
    } else {
      bk[j] = -1;
    }
  }
  __syncthreads();
  for (int i = t; i < NBUCK; i += 256) base[i] = atomicAdd(&gcursor[i], hist[i]);
  __syncthreads();
#pragma unroll
  for (int j = 0; j < EPB; ++j) {
    if (bk[j] >= 0) {
      int pos = base[bk[j]] + rank[j];
      if (pos < CAP) staging[(size_t)bk[j] * CAP + pos] = val[j];
    }
  }
}

// ---------------- pass 2: per-bucket CSR finalize (scan fused in) ----------------
__global__ __launch_bounds__(256) void build_kernel(const int* __restrict__ staging,
                                                    const int* __restrict__ gcursor,
                                                    int* __restrict__ row_off,
                                                    int* __restrict__ esrc) {
  __shared__ int ncnt[512];
  __shared__ int noff[513];
  __shared__ int part[256];
  __shared__ int sscan[256];
  int b = blockIdx.x, t = threadIdx.x;
  int gv = (t < NBUCK) ? gcursor[t] : 0;
  sscan[t] = gv;
  __syncthreads();
  for (int st = 1; st < 256; st <<= 1) {
    int u = (t >= st) ? sscan[t - st] : 0;
    __syncthreads();
    sscan[t] += u;
    __syncthreads();
  }
  int cnt = gcursor[b];
  int ebase = sscan[b] - cnt;  // exclusive prefix
  int nbase = b << BSHIFT;
  ncnt[t] = 0;
  ncnt[t + 256] = 0;
  __syncthreads();
  const int* sp = staging + (size_t)b * CAP;
  for (int i = t; i < cnt; i += 256) {
    int dl = sp[i] >> 17;
    atomicAdd(&ncnt[dl], 1);
  }
  __syncthreads();
  int a0 = ncnt[2 * t], a1 = ncnt[2 * t + 1];
  part[t] = a0 + a1;
  __syncthreads();
  for (int st = 1; st < 256; st <<= 1) {
    int u = (t >= st) ? part[t - st] : 0;
    __syncthreads();
    part[t] += u;
    __syncthreads();
  }
  int excl = (t > 0) ? part[t - 1] : 0;
  noff[2 * t] = excl;
  noff[2 * t + 1] = excl + a0;
  if (t == 255) noff[512] = part[255];
  __syncthreads();
  for (int i = t; i <= 512; i += 256) {
    int n = nbase + i;
    if (n <= NN) row_off[n] = ebase + noff[i];
  }
  ncnt[2 * t] = noff[2 * t];
  ncnt[2 * t + 1] = noff[2 * t + 1];
  __syncthreads();
  for (int i = t; i < cnt; i += 256) {
    int v = sp[i];
    int dl = v >> 17;
    int pos = atomicAdd(&ncnt[dl], 1);
    esrc[ebase + pos] = v & 0x1FFFF;
  }
}

// ---------------- dense GEMM: y = x @ W (no bias/relu; they move to agg) ----
// 512 threads, 64 nodes per block. Streams x (standard or sliced layout) into
// transposed LDS tile, then the proven 4x4-per-thread fp32 GEMM. Output is
// written SLICE-MAJOR for the following aggregate's L2-resident gather.
template <int SLICED_IN>
__global__ __launch_bounds__(512) void gemm_lin(const float* __restrict__ xin,
                                                const float* __restrict__ W,
                                                float* __restrict__ yout) {
  __shared__ __align__(16) float aT[128 * 68];
  int t = threadIdx.x;
  int nodebase = blockIdx.x * 64;

#pragma unroll
  for (int j = 0; j < 4; ++j) {
    int linear = t + j * 512;  // float4 id, 0..2047 (64 nodes x 32 float4)
    float4 v = make_float4(0.f, 0.f, 0.f, 0.f);
    if (SLICED_IN == 0) {
      int node = linear >> 5;
      int q = linear & 31;
      if (nodebase + node < NN)
        v = *(const float4*)(xin + (size_t)(nodebase + node) * FDIM + q * 4);
      aT[(4 * q + 0) * 68 + node] = v.x;
      aT[(4 * q + 1) * 68 + node] = v.y;
      aT[(4 * q + 2) * 68 + node] = v.z;
      aT[(4 * q + 3) * 68 + node] = v.w;
    } else {
      int slice = linear >> 7;  // 128 float4 per slice (64 nodes x 2)
      int r2 = linear & 127;
      int node = r2 >> 1;
      int h = r2 & 1;
      if (nodebase + node < NN)
        v = *(const float4*)(xin + (size_t)slice * SS +
                             (size_t)(nodebase + node) * FS + h * 4);
      int f = slice * 8 + h * 4;
      aT[(f + 0) * 68 + node] = v.x;
      aT[(f + 1) * 68 + node] = v.y;
      aT[(f + 2) * 68 + node] = v.z;
      aT[(f + 3) * 68 + node] = v.w;
    }
  }
  __syncthreads();

  int w = t >> 6;
  int lane = t & 63;
  int rg = lane >> 5;
  int c = lane & 31;
  int rbase = w * 8 + rg * 4;

  float acc[4][4];
#pragma unroll
  for (int r = 0; r < 4; ++r)
#pragma unroll
    for (int j = 0; j < 4; ++j) acc[r][j] = 0.f;

#pragma unroll 4
  for (int k = 0; k < 128; ++k) {
    float4 bv = *(const float4*)(W + k * FDIM + c * 4);
    float4 a0 = *(const float4*)(&aT[k * 68 + rbase]);
    float ar[4] = {a0.x, a0.y, a0.z, a0.w};
#pragma unroll
    for (int r = 0; r < 4; ++r) {
      acc[r][0] += ar[r] * bv.x;
      acc[r][1] += ar[r] * bv.y;
      acc[r][2] += ar[r] * bv.z;
      acc[r][3] += ar[r] * bv.w;
    }
  }

  // sliced store: col group 4c..4c+3 -> slice c/2, offset 4*(c&1)
  int slice = c >> 1;
  int off = (c & 1) * 4;
#pragma unroll
  for (int r = 0; r < 4; ++r) {
    int row = nodebase + rbase + r;
    if (row < NN) {
      float4 o = make_float4(acc[r][0], acc[r][1], acc[r][2], acc[r][3]);
      *(float4*)(yout + (size_t)slice * SS + (size_t)row * FS + off) = o;
    }
  }
}

// ---------------- sliced aggregate: xout = relu(agg(y) + b) --------------
// Grid: 2 phases x 8 slices x 782 tiles, bid = phase*6256 + tile*8 + s so
// that (assumed round-robin) XCD k handles slice k then k+8 -- its 3.2 MB
// y-slice stays L2-resident. 256 threads = 4 waves x 32 lane-pairs; each
// lane-pair owns one dst row and walks its CSR edge list, loading 16B of
// the 32B row-slice per lane. POOL=1 (layer 3): skip x write, fuse the
// graph-sum pool via LDS slots + a few global atomics.
template <int POOL>
__global__ __launch_bounds__(256) void agg_kernel(const float* __restrict__ y,
                                                  const int* __restrict__ row_off,
                                                  const int* __restrict__ esrc,
                                                  const float* __restrict__ bias,
                                                  const int* __restrict__ batching,
                                                  float* __restrict__ xout,
                                                  float* __restrict__ gout) {
  int bid = blockIdx.x;
  const int per_phase = 8 * AGG_NT;  // 6256, multiple of 8
  int phase = bid / per_phase;
  int r = bid - phase * per_phase;
  int slice = phase * 8 + (r & 7);
  int tile = r >> 3;
  int rowbase = tile * AGG_TILE;

  int t = threadIdx.x;
  int wave = t >> 6;
  int lane = t & 63;
  int p = lane >> 1;
  int h4 = (lane & 1) * 4;
  int row = rowbase + wave * 32 + p;
  bool valid = row < NN;
  int beg = 0, end = 0;
  if (valid) {
    beg = row_off[row];
    end = row_off[row + 1];
  }
  const float* ys = y + (size_t)slice * SS;
  float4 acc = make_float4(0.f, 0.f, 0.f, 0.f);
  int e = beg;
  for (; e + 4 <= end; e += 4) {
    int s0 = esrc[e + 0];
    int s1 = esrc[e + 1];
    int s2 = esrc[e + 2];
    int s3 = esrc[e + 3];
    float4 v0 = *(const float4*)(ys + (size_t)s0 * FS + h4);
    float4 v1 = *(const float4*)(ys + (size_t)s1 * FS + h4);
    float4 v2 = *(const float4*)(ys + (size_t)s2 * FS + h4);
    float4 v3 = *(const float4*)(ys + (size_t)s3 * FS + h4);
    acc.x += (v0.x + v1.x) + (v2.x + v3.x);
    acc.y += (v0.y + v1.y) + (v2.y + v3.y);
    acc.z += (v0.z + v1.z) + (v2.z + v3.z);
    acc.w += (v0.w + v1.w) + (v2.w + v3.w);
  }
  for (; e < end; ++e) {
    int s0 = esrc[e];
    float4 v = *(const float4*)(ys + (size_t)s0 * FS + h4);
    acc.x += v.x;
    acc.y += v.y;
    acc.z += v.z;
    acc.w += v.w;
  }
  float4 b4 = *(const float4*)(bias + slice * 8 + h4);
  float4 o;
  o.x = fmaxf(acc.x + b4.x, 0.f);
  o.y = fmaxf(acc.y + b4.y, 0.f);
  o.z = fmaxf(acc.z + b4.z, 0.f);
  o.w = fmaxf(acc.w + b4.w, 0.f);

  if (POOL == 0) {
    if (valid)
      *(float4*)(xout + (size_t)slice * SS + (size_t)row * FS + h4) = o;
  } else {
    // fused global_sum_pool: batching is globally sorted, so a 128-row tile
    // spans ~2-3 graphs. LDS-reduce per graph slot, then one global atomic
    // per (graph, feature). Fallback to direct atomics if >8 graphs.
    __shared__ float gl[8][8];
    __shared__ int sg0, sgn;
    if (t == 0) {
      sg0 = batching[rowbase];
      int last = rowbase + AGG_TILE - 1;
      if (last >= NN) last = NN - 1;
      sgn = batching[last] - sg0 + 1;
    }
    if (t < 64) gl[t >> 3][t & 7] = 0.f;
    __syncthreads();
    int nG = sgn;
    if (nG <= 8) {
      if (valid) {
        int slot = batching[row] - sg0;
        atomicAdd(&gl[slot][h4 + 0], o.x);
        atomicAdd(&gl[slot][h4 + 1], o.y);
        atomicAdd(&gl[slot][h4 + 2], o.z);
        atomicAdd(&gl[slot][h4 + 3], o.w);
      }
      __syncthreads();
      if (t < nG * 8) {
        int slot = t >> 3;
        int f = t & 7;
        float v = gl[slot][f];
        if (v != 0.f)
          atomicAdd(&gout[(size_t)(sg0 + slot) * FDIM + slice * 8 + f], v);
      }
    } else {
      if (valid) {
        int gid = batching[row];
        atomicAdd(&gout[(size_t)gid * FDIM + slice * 8 + h4 + 0], o.x);
        atomicAdd(&gout[(size_t)gid * FDIM + slice * 8 + h4 + 1], o.y);
        atomicAdd(&gout[(size_t)gid * FDIM + slice * 8 + h4 + 2], o.z);
        atomicAdd(&gout[(size_t)gid * FDIM + slice * 8 + h4 + 3], o.w);
      }
    }
  }
}

// ---------------- head: FC1 + FC2 + softmax over pooled g ----------------
__global__ __launch_bounds__(128) void head(const float* __restrict__ g,
                                            const float* __restrict__ Wf1,
                                            const float* __restrict__ bf1,
                                            const float* __restrict__ Wf2,
                                            const float* __restrict__ bf2,
                                            float* __restrict__ out) {
  __shared__ float gl[128];
  __shared__ float hl[64];
  __shared__ float ol[10];
  __shared__ float red[2];
  int gid = blockIdx.x, t = threadIdx.x;
  gl[t] = g[(size_t)gid * FDIM + t];
  __syncthreads();
  if (t < NFC1) {
    float h = bf1[t];
    for (int f = 0; f < 128; ++f) h += gl[f] * Wf1[f * NFC1 + t];
    hl[t] = h;
  }
  __syncthreads();
  if (t < NFC2) {
    float o = bf2[t];
    for (int i = 0; i < NFC1; ++i) o += hl[i] * Wf2[i * NFC2 + t];
    ol[t] = o;
  }
  __syncthreads();
  if (t == 0) {
    float m = ol[0];
    for (int i = 1; i < NFC2; ++i) m = fmaxf(m, ol[i]);
    float s = 0.f;
    for (int i = 0; i < NFC2; ++i) s += expf(ol[i] - m);
    red[0] = m;
    red[1] = s;
  }
  __syncthreads();
  if (t < NFC2) out[(size_t)gid * NFC2 + t] = expf(ol[t] - red[0]) / red[1];
}

extern "C" void kernel_launch(void* const* d_in, const int* in_sizes, int n_in,
                              void* d_out, int out_size, void* d_ws, size_t ws_size,
                              hipStream_t stream) {
  const float* node_attr = (const float*)d_in[0];
  const float* Wc = (const float*)d_in[1];   // [3][128][128]
  const float* bc = (const float*)d_in[2];   // [3][128]
  const float* Wf1 = (const float*)d_in[3];  // [128][64]
  const float* bf1 = (const float*)d_in[4];
  const float* Wf2 = (const float*)d_in[5];  // [64][10]
  const float* bf2 = (const float*)d_in[6];
  const int* src = (const int*)d_in[7];
  const int* dst = (const int*)d_in[8];
  const int* batching = (const int*)d_in[9];
  float* out = (float*)d_out;

  char* wsp = (char*)d_ws;
  size_t off = 0;
  auto alloc = [&](size_t bytes) -> void* {
    void* p = wsp + off;
    off += (bytes + 255) & ~(size_t)255;
    return p;
  };
  int* row_off = (int*)alloc((size_t)(NN + 1) * sizeof(int));
  int* gcursor = (int*)alloc(NBUCK * sizeof(int));
  int* esrc = (int*)alloc((size_t)NE * sizeof(int));
  float* P = (float*)alloc((size_t)NS * SS * sizeof(float));  // 51.2 MB, sliced x
  float* Q = (float*)alloc((size_t)NS * SS * sizeof(float));  // 51.2 MB, sliced y
  // staging (16.1 MB) aliases Q: staging is dead before gemm1 writes Q
  int* staging = (int*)Q;
  // pooled g (512 KB) aliases P: P is dead after gemm3 reads it
  float* gbuf = (float*)P;

  const int GEMM_GRID = (NN + 63) / 64;           // 1563
  const int AGG_GRID = 2 * 8 * AGG_NT;            // 12512

  // CSR build via 2-level counting sort
  hipMemsetAsync(gcursor, 0, NBUCK * sizeof(int), stream);
  bin_kernel<<<(NE + 256 * EPB - 1) / (256 * EPB), 256, 0, stream>>>(src, dst, gcursor, staging);
  build_kernel<<<NBUCK, 256, 0, stream>>>(staging, gcursor, row_off, esrc);

  // layer 1: y = node_attr @ W0 ; x2 = relu(agg(y) + b0)
  gemm_lin<0><<<GEMM_GRID, 512, 0, stream>>>(node_attr, Wc, Q);
  agg_kernel<0><<<AGG_GRID, 256, 0, stream>>>(Q, row_off, esrc, bc, nullptr, P, nullptr);

  // layer 2
  gemm_lin<1><<<GEMM_GRID, 512, 0, stream>>>(P, Wc + 16384, Q);
  agg_kernel<0><<<AGG_GRID, 256, 0, stream>>>(Q, row_off, esrc, bc + 128, nullptr, P, nullptr);

  // layer 3: gemm, then aggregate fused with global_sum_pool (no x3 write)
  gemm_lin<1><<<GEMM_GRID, 512, 0, stream>>>(P, Wc + 32768, Q);
  hipMemsetAsync(gbuf, 0, (size_t)NG * FDIM * sizeof(float), stream);
  agg_kernel<1><<<AGG_GRID, 256, 0, stream>>>(Q, row_off, esrc, bc + 256, batching, nullptr, gbuf);

  // head
  head<<<NG, 128, 0, stream>>>(gbuf, Wf1, bf1, Wf2, bf2, out);
}